// Round 4
// baseline (310.236 us; speedup 1.0000x reference)
//
#include <hip/hip_runtime.h>

#define K_CODES 512
#define DIM     256
#define HW      1024          // 32*32
#define N_ROWS  65536         // 64*32*32
#define BM      64
#define BK      128
#define BD      32
#define NT      256

#define OUT_Q_OFF    16777216 // 64*256*32*32 (fp32 elements)
#define OUT_LOSS_OFF 16842752

// ws layout (floats): [0,512) c2[k] ; [512,1536) per-block dist partials ; [1536,2560) per-block x2 partials
#define WS_DIST 512
#define WS_X2   1536

__global__ void c2_kernel(const float* __restrict__ lut, float* __restrict__ ws) {
    int t = threadIdx.x;
    for (int k = t; k < K_CODES; k += NT) {
        const float* row = lut + (size_t)k * DIM;
        float s = 0.f;
        for (int i = 0; i < DIM; ++i) s += row[i] * row[i];
        ws[k] = s;
    }
}

__global__ __launch_bounds__(NT) void vq_kernel(const float* __restrict__ x,
                                                const float* __restrict__ lut,
                                                float* __restrict__ out,
                                                float* __restrict__ ws) {
    __shared__ float xs[BD][BM];       // 8 KB
    __shared__ float ls[BD][BK];       // 16 KB
    __shared__ float c2s[K_CODES];     // 2 KB
    __shared__ float redv[16][BM];     // 4 KB
    __shared__ int   redi[16][BM];     // 4 KB
    __shared__ float wsum[4];

    const int tid = threadIdx.x;
    const int blk = blockIdx.x;
    const int n0  = blk * BM;
    const int b   = n0 >> 10;
    const int hw0 = n0 & 1023;
    const float* xb = x + (size_t)b * (DIM * HW) + hw0;   // xb[d*HW + m]

    for (int k = tid; k < K_CODES; k += NT) c2s[k] = ws[k];

    const int tm = tid & 15;    // rows tm*4 .. tm*4+3
    const int tk = tid >> 4;    // codes tk*8 .. tk*8+7 within BK chunk

    float bestd[4];
    int   besti[4];
    #pragma unroll
    for (int i = 0; i < 4; ++i) { bestd[i] = 3.4e38f; besti[i] = 0; }

    float x2local = 0.f;

    // staging maps
    const int sx_dd = tid >> 3;          // 0..31
    const int sx_m0 = (tid & 7) * 8;     // 0..56
    const int sl_k  = tid & 127;         // 0..127
    const int sl_dg = tid >> 7;          // 0..1

    for (int kc = 0; kc < K_CODES / BK; ++kc) {
        float acc[4][8];
        #pragma unroll
        for (int i = 0; i < 4; ++i)
            #pragma unroll
            for (int j = 0; j < 8; ++j) acc[i][j] = 0.f;

        const float* lb = lut + (size_t)(kc * BK) * DIM;

        for (int dc = 0; dc < DIM / BD; ++dc) {
            __syncthreads();   // previous tile fully consumed before overwrite
            // stage x tile: xs[dd][m] = x[b][dc*BD+dd][hw0+m]
            {
                const float* src = xb + (size_t)(dc * BD + sx_dd) * HW + sx_m0;
                #pragma unroll
                for (int j = 0; j < 8; ++j) {
                    float v = src[j];
                    xs[sx_dd][sx_m0 + j] = v;
                    if (kc == 0) x2local += v * v;
                }
            }
            // stage lut tile transposed: ls[dd][k] = lut[kc*BK+k][dc*BD+dd]
            {
                const float* src = lb + (size_t)sl_k * DIM + dc * BD + sl_dg * 16;
                #pragma unroll
                for (int j = 0; j < 16; ++j) {
                    ls[sl_dg * 16 + j][sl_k] = src[j];
                }
            }
            __syncthreads();
            #pragma unroll 4
            for (int dd = 0; dd < BD; ++dd) {
                float a0 = xs[dd][tm * 4 + 0];
                float a1 = xs[dd][tm * 4 + 1];
                float a2 = xs[dd][tm * 4 + 2];
                float a3 = xs[dd][tm * 4 + 3];
                #pragma unroll
                for (int j = 0; j < 8; ++j) {
                    float l = ls[dd][tk * 8 + j];
                    acc[0][j] = fmaf(a0, l, acc[0][j]);
                    acc[1][j] = fmaf(a1, l, acc[1][j]);
                    acc[2][j] = fmaf(a2, l, acc[2][j]);
                    acc[3][j] = fmaf(a3, l, acc[3][j]);
                }
            }
        }
        // fold chunk into running best (code-ascending => first-min tie-break)
        #pragma unroll
        for (int j = 0; j < 8; ++j) {
            int code = kc * BK + tk * 8 + j;
            float c2 = c2s[code];
            #pragma unroll
            for (int i = 0; i < 4; ++i) {
                float dist = fmaf(-2.f, acc[i][j], c2);
                if (dist < bestd[i]) { bestd[i] = dist; besti[i] = code; }
            }
        }
    }

    __syncthreads();
    #pragma unroll
    for (int i = 0; i < 4; ++i) {
        redv[tk][tm * 4 + i] = bestd[i];
        redi[tk][tm * 4 + i] = besti[i];
    }
    __syncthreads();

    float distsum_part = 0.f;
    if (tid < BM) {
        const int row = tid;
        float bv = redv[0][row];
        int   bi = redi[0][row];
        #pragma unroll
        for (int t = 1; t < 16; ++t) {
            float v = redv[t][row];
            int   ii = redi[t][row];
            if (v < bv || (v == bv && ii < bi)) { bv = v; bi = ii; }
        }
        out[OUT_Q_OFF + n0 + row] = (float)bi;   // fp32 q; gather re-reads this
        distsum_part = bv;
    }

    // block reductions (deterministic): x2 over all 256 lanes, dist over wave 0
    float v = x2local;
    #pragma unroll
    for (int off = 32; off; off >>= 1) v += __shfl_down(v, off, 64);
    if ((tid & 63) == 0) wsum[tid >> 6] = v;
    float dv = distsum_part;
    #pragma unroll
    for (int off = 32; off; off >>= 1) dv += __shfl_down(dv, off, 64);
    __syncthreads();
    if (tid == 0) {
        float x2 = wsum[0] + wsum[1] + wsum[2] + wsum[3];
        ws[WS_DIST + blk] = dv;
        ws[WS_X2 + blk]   = x2;
    }
}

// Standalone gather: overwrites the ENTIRE x_e region (fp32) from q (read back from out) + lut.
__global__ void gather_kernel(const float* __restrict__ lut,
                              float* __restrict__ out) {
    const long long stride = (long long)gridDim.x * NT;
    for (long long idx = (long long)blockIdx.x * NT + threadIdx.x;
         idx < 16777216LL; idx += stride) {
        int b  = (int)(idx >> 18);          // / 262144
        int d  = (int)(idx >> 10) & 255;
        int hw = (int)idx & 1023;
        int qi = (int)out[OUT_Q_OFF + (b << 10) + hw];
        out[idx] = lut[qi * DIM + d];
    }
}

__global__ void loss_kernel(float* __restrict__ out, const float* __restrict__ ws) {
    __shared__ float wsum[4];
    int tid = threadIdx.x;
    float s = 0.f;
    for (int i = tid; i < 2048; i += NT) s += ws[WS_DIST + i];   // dist + x2 ranges
    #pragma unroll
    for (int off = 32; off; off >>= 1) s += __shfl_down(s, off, 64);
    if ((tid & 63) == 0) wsum[tid >> 6] = s;
    __syncthreads();
    if (tid == 0) {
        float total = wsum[0] + wsum[1] + wsum[2] + wsum[3];
        out[OUT_LOSS_OFF] = total * (1.25f / 16777216.f);   // (1+BETA) * mean
    }
}

extern "C" void kernel_launch(void* const* d_in, const int* in_sizes, int n_in,
                              void* d_out, int out_size, void* d_ws, size_t ws_size,
                              hipStream_t stream) {
    const float* x   = (const float*)d_in[0];
    const float* lut = (const float*)d_in[1];
    float* out = (float*)d_out;
    float* ws  = (float*)d_ws;

    c2_kernel<<<1, NT, 0, stream>>>(lut, ws);
    vq_kernel<<<N_ROWS / BM, NT, 0, stream>>>(x, lut, out, ws);
    gather_kernel<<<8192, NT, 0, stream>>>(lut, out);
    loss_kernel<<<1, NT, 0, stream>>>(out, ws);
}

// Round 5
// 284.933 us; speedup vs baseline: 1.0888x; 1.0888x over previous
//
#include <hip/hip_runtime.h>

#define K_CODES 512
#define DIM     256
#define HW      1024          // 32*32
#define N_ROWS  65536         // 64*32*32
#define BM      128
#define BK      128
#define BD      32
#define NT      256
#define NBLK    (N_ROWS / BM) // 512

#define OUT_Q_OFF    16777216 // 64*256*32*32 (fp32 elements)
#define OUT_LOSS_OFF 16842752

// ws layout (floats): [0,512) c2[k] ; [512,1024) per-block dist partials ; [1024,1536) per-block x2 partials
#define WS_DIST 512
#define WS_X2   1024

__global__ void c2_kernel(const float* __restrict__ lut, float* __restrict__ ws) {
    int t = threadIdx.x;
    for (int k = t; k < K_CODES; k += NT) {
        const float4* row = (const float4*)(lut + (size_t)k * DIM);
        float s = 0.f;
        #pragma unroll 8
        for (int i = 0; i < DIM / 4; ++i) {
            float4 v = row[i];
            s += v.x * v.x + v.y * v.y + v.z * v.z + v.w * v.w;
        }
        ws[k] = s;
    }
}

__global__ __launch_bounds__(NT) void vq_kernel(const float* __restrict__ x,
                                                const float* __restrict__ lut,
                                                float* __restrict__ out,
                                                float* __restrict__ ws) {
    __shared__ float xs[BD][BM];       // 16 KB
    __shared__ float ls[BD][BK];       // 16 KB
    __shared__ float c2s[K_CODES];     // 2 KB
    __shared__ float redv[4][BM];      // 2 KB
    __shared__ int   redi[4][BM];      // 2 KB
    __shared__ float wsumd[4];
    __shared__ float wsumx[4];

    const int tid = threadIdx.x;
    const int blk = blockIdx.x;
    const int n0  = blk * BM;
    const int b   = n0 >> 10;
    const int hw0 = n0 & 1023;
    const float* xb = x + (size_t)b * (DIM * HW) + hw0;   // xb[d*HW + m]

    for (int k = tid; k < K_CODES; k += NT) c2s[k] = ws[k];

    const int tm = tid & 15;      // rows tm*8 .. tm*8+7
    const int tk = tid >> 4;      // codes tk*8 .. tk*8+7 within BK chunk

    // staging maps
    const int sx_dg = (tid >> 5) * 4;    // x: dd base (0,4,...,28)
    const int sx_m0 = (tid & 31) * 4;    // x: col (0..124)
    const int sl_k  = tid >> 3;          // ls: k base (0..31)
    const int sl_d0 = (tid & 7) * 4;     // ls: dd base (0..28)

    float bestd[8];
    int   besti[8];
    #pragma unroll
    for (int i = 0; i < 8; ++i) { bestd[i] = 3.4e38f; besti[i] = 0; }

    float x2local = 0.f;

    for (int kc = 0; kc < K_CODES / BK; ++kc) {
        float acc[8][8];
        #pragma unroll
        for (int i = 0; i < 8; ++i)
            #pragma unroll
            for (int j = 0; j < 8; ++j) acc[i][j] = 0.f;

        const float* lb = lut + (size_t)(kc * BK) * DIM;

        for (int dc = 0; dc < DIM / BD; ++dc) {
            __syncthreads();   // previous tile fully consumed before overwrite
            // stage x tile: xs[dd][m], vectorized (conflict-free b128 writes)
            #pragma unroll
            for (int j = 0; j < 4; ++j) {
                int dd = sx_dg + j;
                const float* src = xb + (size_t)(dc * BD + dd) * HW + sx_m0;
                float4 v = *(const float4*)src;
                *(float4*)&xs[dd][sx_m0] = v;
                if (kc == 0) x2local += v.x*v.x + v.y*v.y + v.z*v.z + v.w*v.w;
            }
            // stage lut tile transposed: ls[dd][k] = lut[kc*BK+k][dc*BD+dd]
            #pragma unroll
            for (int p = 0; p < 4; ++p) {
                int k0 = sl_k + p * 32;
                float4 v = *(const float4*)(lb + (size_t)k0 * DIM + dc * BD + sl_d0);
                ls[sl_d0 + 0][k0] = v.x;
                ls[sl_d0 + 1][k0] = v.y;
                ls[sl_d0 + 2][k0] = v.z;
                ls[sl_d0 + 3][k0] = v.w;
            }
            __syncthreads();
            #pragma unroll 4
            for (int dd = 0; dd < BD; ++dd) {
                float4 a0 = *(const float4*)&xs[dd][tm * 8];
                float4 a1 = *(const float4*)&xs[dd][tm * 8 + 4];
                float4 l0 = *(const float4*)&ls[dd][tk * 8];
                float4 l1 = *(const float4*)&ls[dd][tk * 8 + 4];
                float av[8] = {a0.x, a0.y, a0.z, a0.w, a1.x, a1.y, a1.z, a1.w};
                float lv[8] = {l0.x, l0.y, l0.z, l0.w, l1.x, l1.y, l1.z, l1.w};
                #pragma unroll
                for (int i = 0; i < 8; ++i)
                    #pragma unroll
                    for (int j = 0; j < 8; ++j)
                        acc[i][j] = fmaf(av[i], lv[j], acc[i][j]);
            }
        }
        // fold chunk into running best (code-ascending => first-min tie-break)
        #pragma unroll
        for (int j = 0; j < 8; ++j) {
            int code = kc * BK + tk * 8 + j;
            float c2 = c2s[code];
            #pragma unroll
            for (int i = 0; i < 8; ++i) {
                float dist = fmaf(-2.f, acc[i][j], c2);
                if (dist < bestd[i]) { bestd[i] = dist; besti[i] = code; }
            }
        }
    }

    // cross-thread argmin: butterfly over the 4 tk-groups within each wave
    #pragma unroll
    for (int i = 0; i < 8; ++i) {
        #pragma unroll
        for (int off = 16; off < 64; off <<= 1) {
            float ov = __shfl_xor(bestd[i], off, 64);
            int   oi = __shfl_xor(besti[i], off, 64);
            if (ov < bestd[i] || (ov == bestd[i] && oi < besti[i])) {
                bestd[i] = ov; besti[i] = oi;
            }
        }
    }
    const int wave = tid >> 6;
    if ((tid & 63) < 16) {
        #pragma unroll
        for (int i = 0; i < 8; ++i) {
            redv[wave][tm * 8 + i] = bestd[i];
            redi[wave][tm * 8 + i] = besti[i];
        }
    }
    __syncthreads();

    float distsum_part = 0.f;
    if (tid < BM) {
        const int m = tid;
        float bv = redv[0][m];
        int   bi = redi[0][m];
        #pragma unroll
        for (int w = 1; w < 4; ++w) {
            float v = redv[w][m];
            int   ii = redi[w][m];
            if (v < bv || (v == bv && ii < bi)) { bv = v; bi = ii; }
        }
        out[OUT_Q_OFF + n0 + m] = (float)bi;   // fp32 q; gather re-reads this
        distsum_part = bv;
    }

    // deterministic block reductions
    float dv = distsum_part;
    #pragma unroll
    for (int off = 32; off; off >>= 1) dv += __shfl_down(dv, off, 64);
    if ((tid & 63) == 0) wsumd[wave] = dv;
    float v = x2local;
    #pragma unroll
    for (int off = 32; off; off >>= 1) v += __shfl_down(v, off, 64);
    if ((tid & 63) == 0) wsumx[wave] = v;
    __syncthreads();
    if (tid == 0) {
        ws[WS_DIST + blk] = wsumd[0] + wsumd[1] + wsumd[2] + wsumd[3];
        ws[WS_X2 + blk]   = wsumx[0] + wsumx[1] + wsumx[2] + wsumx[3];
    }
}

// Standalone gather: overwrites the ENTIRE x_e region (fp32) from q (read back from out) + lut.
__global__ void gather_kernel(const float* __restrict__ lut,
                              float* __restrict__ out) {
    const long long stride = (long long)gridDim.x * NT;
    for (long long idx = (long long)blockIdx.x * NT + threadIdx.x;
         idx < 16777216LL; idx += stride) {
        int b  = (int)(idx >> 18);          // / 262144
        int d  = (int)(idx >> 10) & 255;
        int hw = (int)idx & 1023;
        int qi = (int)out[OUT_Q_OFF + (b << 10) + hw];
        out[idx] = lut[qi * DIM + d];
    }
}

__global__ void loss_kernel(float* __restrict__ out, const float* __restrict__ ws) {
    __shared__ float wsum[4];
    int tid = threadIdx.x;
    float s = 0.f;
    for (int i = tid; i < 1024; i += NT) s += ws[WS_DIST + i];   // dist [512,1024) + x2 [1024,1536)
    #pragma unroll
    for (int off = 32; off; off >>= 1) s += __shfl_down(s, off, 64);
    if ((tid & 63) == 0) wsum[tid >> 6] = s;
    __syncthreads();
    if (tid == 0) {
        float total = wsum[0] + wsum[1] + wsum[2] + wsum[3];
        out[OUT_LOSS_OFF] = total * (1.25f / 16777216.f);   // (1+BETA) * mean
    }
}

extern "C" void kernel_launch(void* const* d_in, const int* in_sizes, int n_in,
                              void* d_out, int out_size, void* d_ws, size_t ws_size,
                              hipStream_t stream) {
    const float* x   = (const float*)d_in[0];
    const float* lut = (const float*)d_in[1];
    float* out = (float*)d_out;
    float* ws  = (float*)d_ws;

    c2_kernel<<<1, NT, 0, stream>>>(lut, ws);
    vq_kernel<<<NBLK, NT, 0, stream>>>(x, lut, out, ws);
    gather_kernel<<<8192, NT, 0, stream>>>(lut, out);
    loss_kernel<<<1, NT, 0, stream>>>(out, ws);
}

// Round 6
// 277.600 us; speedup vs baseline: 1.1176x; 1.0264x over previous
//
#include <hip/hip_runtime.h>

#define K_CODES 512
#define DIM     256
#define HW      1024          // 32*32
#define N_ROWS  65536         // 64*32*32
#define BM      128
#define BK      128
#define BD      32
#define NT      256
#define NBLK    (N_ROWS / BM) // 512

#define OUT_Q_OFF    16777216 // 64*256*32*32 (fp32 elements)
#define OUT_LOSS_OFF 16842752

// ws layout (floats): [0,512) c2[k] ; [512,1024) per-block dist partials ; [1024,1536) per-block x2 partials
#define WS_DIST 512
#define WS_X2   1024

__global__ void c2_kernel(const float* __restrict__ lut, float* __restrict__ ws) {
    int t = threadIdx.x;
    for (int k = t; k < K_CODES; k += NT) {
        const float4* row = (const float4*)(lut + (size_t)k * DIM);
        float s = 0.f;
        #pragma unroll 8
        for (int i = 0; i < DIM / 4; ++i) {
            float4 v = row[i];
            s += v.x * v.x + v.y * v.y + v.z * v.z + v.w * v.w;
        }
        ws[k] = s;
    }
}

__global__ __launch_bounds__(NT) void vq_kernel(const float* __restrict__ x,
                                                const float* __restrict__ lut,
                                                float* __restrict__ out,
                                                float* __restrict__ ws) {
    __shared__ float xs[BD][BM];       // 16 KB
    __shared__ float ls[BD][BK];       // 16 KB
    __shared__ float c2s[K_CODES];     // 2 KB
    __shared__ float redv[4][BM];      // 2 KB
    __shared__ int   redi[4][BM];      // 2 KB
    __shared__ float wsumd[4];
    __shared__ float wsumx[4];

    const int tid = threadIdx.x;
    const int blk = blockIdx.x;
    const int n0  = blk * BM;
    const int b   = n0 >> 10;
    const int hw0 = n0 & 1023;
    const float* xb = x + (size_t)b * (DIM * HW) + hw0;   // xb[d*HW + m]

    for (int k = tid; k < K_CODES; k += NT) c2s[k] = ws[k];

    const int tm = tid & 15;      // rows {tm*4+i, 64+tm*4+i}
    const int tk = tid >> 4;      // codes tk*8 .. tk*8+7 within BK chunk (tk 0..15 over block)

    // staging maps
    const int sx_dg = (tid >> 5) * 4;    // x: dd base (0,4,...,28)
    const int sx_m0 = (tid & 31) * 4;    // x: col (0..124)
    const int sl_k  = tid & 31;          // ls: k within 32-chunk (conflict-free bank map)
    const int sl_d0 = (tid >> 5) * 4;    // ls: dd base (0..28)

    float bestd[8];
    int   besti[8];
    #pragma unroll
    for (int i = 0; i < 8; ++i) { bestd[i] = 3.4e38f; besti[i] = 0; }

    float x2local = 0.f;

    for (int kc = 0; kc < K_CODES / BK; ++kc) {
        float acc[8][8];
        #pragma unroll
        for (int i = 0; i < 8; ++i)
            #pragma unroll
            for (int j = 0; j < 8; ++j) acc[i][j] = 0.f;

        const float* lb = lut + (size_t)(kc * BK) * DIM;

        for (int dc = 0; dc < DIM / BD; ++dc) {
            __syncthreads();   // previous tile fully consumed before overwrite
            // stage x tile: xs[dd][m], b128 writes, conflict-free
            #pragma unroll
            for (int j = 0; j < 4; ++j) {
                int dd = sx_dg + j;
                const float* src = xb + (size_t)(dc * BD + dd) * HW + sx_m0;
                float4 v = *(const float4*)src;
                *(float4*)&xs[dd][sx_m0] = v;
                if (kc == 0) x2local += v.x*v.x + v.y*v.y + v.z*v.z + v.w*v.w;
            }
            // stage lut tile transposed: ls[dd][k] = lut[kc*BK+k][dc*BD+dd]
            // lane map: k = sl_k (+p*32)  -> 32 distinct banks per wave, 2-way (free)
            #pragma unroll
            for (int p = 0; p < 4; ++p) {
                int k0 = sl_k + p * 32;
                float4 v = *(const float4*)(lb + (size_t)k0 * DIM + dc * BD + sl_d0);
                ls[sl_d0 + 0][k0] = v.x;
                ls[sl_d0 + 1][k0] = v.y;
                ls[sl_d0 + 2][k0] = v.z;
                ls[sl_d0 + 3][k0] = v.w;
            }
            __syncthreads();
            #pragma unroll 4
            for (int dd = 0; dd < BD; ++dd) {
                float4 a0 = *(const float4*)&xs[dd][tm * 4];        // rows tm*4..tm*4+3
                float4 a1 = *(const float4*)&xs[dd][64 + tm * 4];   // rows 64+tm*4..+3
                float4 l0 = *(const float4*)&ls[dd][tk * 8];
                float4 l1 = *(const float4*)&ls[dd][tk * 8 + 4];
                float av[8] = {a0.x, a0.y, a0.z, a0.w, a1.x, a1.y, a1.z, a1.w};
                float lv[8] = {l0.x, l0.y, l0.z, l0.w, l1.x, l1.y, l1.z, l1.w};
                #pragma unroll
                for (int i = 0; i < 8; ++i)
                    #pragma unroll
                    for (int j = 0; j < 8; ++j)
                        acc[i][j] = fmaf(av[i], lv[j], acc[i][j]);
            }
        }
        // fold chunk into running best (code-ascending => first-min tie-break)
        #pragma unroll
        for (int j = 0; j < 8; ++j) {
            int code = kc * BK + tk * 8 + j;
            float c2 = c2s[code];
            #pragma unroll
            for (int i = 0; i < 8; ++i) {
                float dist = fmaf(-2.f, acc[i][j], c2);
                if (dist < bestd[i]) { bestd[i] = dist; besti[i] = code; }
            }
        }
    }

    // cross-thread argmin: butterfly over the 4 tk-groups within each wave
    #pragma unroll
    for (int i = 0; i < 8; ++i) {
        #pragma unroll
        for (int off = 16; off < 64; off <<= 1) {
            float ov = __shfl_xor(bestd[i], off, 64);
            int   oi = __shfl_xor(besti[i], off, 64);
            if (ov < bestd[i] || (ov == bestd[i] && oi < besti[i])) {
                bestd[i] = ov; besti[i] = oi;
            }
        }
    }
    const int wave = tid >> 6;
    if ((tid & 63) < 16) {
        #pragma unroll
        for (int i = 0; i < 8; ++i) {
            int m = (i < 4) ? (tm * 4 + i) : (64 + tm * 4 + (i - 4));
            redv[wave][m] = bestd[i];
            redi[wave][m] = besti[i];
        }
    }
    __syncthreads();

    float distsum_part = 0.f;
    if (tid < BM) {
        const int m = tid;
        float bv = redv[0][m];
        int   bi = redi[0][m];
        #pragma unroll
        for (int w = 1; w < 4; ++w) {
            float v = redv[w][m];
            int   ii = redi[w][m];
            if (v < bv || (v == bv && ii < bi)) { bv = v; bi = ii; }
        }
        out[OUT_Q_OFF + n0 + m] = (float)bi;   // fp32 q; gather re-reads this
        distsum_part = bv;
    }

    // deterministic block reductions
    float dv = distsum_part;
    #pragma unroll
    for (int off = 32; off; off >>= 1) dv += __shfl_down(dv, off, 64);
    if ((tid & 63) == 0) wsumd[wave] = dv;
    float v = x2local;
    #pragma unroll
    for (int off = 32; off; off >>= 1) v += __shfl_down(v, off, 64);
    if ((tid & 63) == 0) wsumx[wave] = v;
    __syncthreads();
    if (tid == 0) {
        ws[WS_DIST + blk] = wsumd[0] + wsumd[1] + wsumd[2] + wsumd[3];
        ws[WS_X2 + blk]   = wsumx[0] + wsumx[1] + wsumx[2] + wsumx[3];
    }
}

// Standalone gather: overwrites the ENTIRE x_e region (fp32) from q (read back from out) + lut.
__global__ void gather_kernel(const float* __restrict__ lut,
                              float* __restrict__ out) {
    const long long stride = (long long)gridDim.x * NT;
    for (long long idx = (long long)blockIdx.x * NT + threadIdx.x;
         idx < 16777216LL; idx += stride) {
        int b  = (int)(idx >> 18);          // / 262144
        int d  = (int)(idx >> 10) & 255;
        int hw = (int)idx & 1023;
        int qi = (int)out[OUT_Q_OFF + (b << 10) + hw];
        out[idx] = lut[qi * DIM + d];
    }
}

__global__ void loss_kernel(float* __restrict__ out, const float* __restrict__ ws) {
    __shared__ float wsum[4];
    int tid = threadIdx.x;
    float s = 0.f;
    for (int i = tid; i < 1024; i += NT) s += ws[WS_DIST + i];   // dist [512,1024) + x2 [1024,1536)
    #pragma unroll
    for (int off = 32; off; off >>= 1) s += __shfl_down(s, off, 64);
    if ((tid & 63) == 0) wsum[tid >> 6] = s;
    __syncthreads();
    if (tid == 0) {
        float total = wsum[0] + wsum[1] + wsum[2] + wsum[3];
        out[OUT_LOSS_OFF] = total * (1.25f / 16777216.f);   // (1+BETA) * mean
    }
}

extern "C" void kernel_launch(void* const* d_in, const int* in_sizes, int n_in,
                              void* d_out, int out_size, void* d_ws, size_t ws_size,
                              hipStream_t stream) {
    const float* x   = (const float*)d_in[0];
    const float* lut = (const float*)d_in[1];
    float* out = (float*)d_out;
    float* ws  = (float*)d_ws;

    c2_kernel<<<1, NT, 0, stream>>>(lut, ws);
    vq_kernel<<<NBLK, NT, 0, stream>>>(x, lut, out, ws);
    gather_kernel<<<8192, NT, 0, stream>>>(lut, out);
    loss_kernel<<<1, NT, 0, stream>>>(out, ws);
}